// Round 2
// baseline (25662.103 us; speedup 1.0000x reference)
//
#include <hip/hip_runtime.h>
#include <hip/hip_bf16.h>

#define NN 50000
#define NE 1000000
#define NG 256
#define NL 6

__device__ __forceinline__ float siluf(float v){ return v / (1.0f + expf(-v)); }

// ---- in-degree count ----
__global__ void k_count(const int* __restrict__ ei, int* __restrict__ cnt){
  int e = blockIdx.x*256 + threadIdx.x;
  if (e<NE) atomicAdd(&cnt[ei[NE+e]], 1);
}

// ---- init coords f32 copy + 1/max(cnt,1) ----
__global__ void k_prep(const float* __restrict__ coords,
                       const int* __restrict__ cnt,
                       float* __restrict__ x, float* __restrict__ cntinv){
  int n = blockIdx.x*256+threadIdx.x;
  if (n<NN){
    x[n*3+0]=coords[n*3+0];
    x[n*3+1]=coords[n*3+1];
    x[n*3+2]=coords[n*3+2];
    cntinv[n]=1.0f/fmaxf((float)cnt[n],1.0f);
  }
}

// ---- encoder: h = silu(nf@w1+b1)@w2+b2 ; one wave per node, lane -> 2 outputs ----
__global__ void k_encoder(const float* __restrict__ nf,
                          const float* __restrict__ w1, const float* __restrict__ b1,
                          const float* __restrict__ w2, const float* __restrict__ b2,
                          float* __restrict__ h){
  int wl = threadIdx.x>>6, lane = threadIdx.x&63;
  int n = blockIdx.x*4 + wl;
  __shared__ float t1s[4][128];
  const float* nfp = nf + (size_t)n*16;
  float a0=b1[2*lane], a1=b1[2*lane+1];
  #pragma unroll
  for(int k=0;k<16;k++){
    float m = nfp[k];
    float2 w = ((const float2*)(w1+k*128))[lane];
    a0 += m*w.x; a1 += m*w.y;
  }
  t1s[wl][2*lane]=siluf(a0); t1s[wl][2*lane+1]=siluf(a1);
  __syncthreads();
  float c0=b2[2*lane], c1=b2[2*lane+1];
  for(int k=0;k<128;k++){
    float m = t1s[wl][k];
    float2 w = ((const float2*)(w2+k*128))[lane];
    c0 += m*w.x; c1 += m*w.y;
  }
  h[(size_t)n*128+2*lane]=c0; h[(size_t)n*128+2*lane+1]=c1;
}

// ---- per-layer node precompute: pa = b1 + h@W1[0:128], pb = h@W1[128:256] ----
__global__ void k_pre(const float* __restrict__ h,
                      const float* __restrict__ w1, const float* __restrict__ b1,
                      float* __restrict__ pa, float* __restrict__ pb){
  int wl = threadIdx.x>>6, lane = threadIdx.x&63;
  int n = blockIdx.x*4+wl;
  __shared__ float hs[4][128];
  hs[wl][2*lane]  =h[(size_t)n*128+2*lane];
  hs[wl][2*lane+1]=h[(size_t)n*128+2*lane+1];
  __syncthreads();
  float a=b1[lane], b=0.f;
  for(int k=0;k<128;k++){
    float m = hs[wl][k];
    a += m*w1[k*64+lane];
    b += m*w1[(128+k)*64+lane];
  }
  pa[(size_t)n*64+lane]=a; pb[(size_t)n*64+lane]=b;
}

// ---- edge kernel: thread per edge, wave-uniform weight loads ----
__global__ void __launch_bounds__(256,1)
k_edge(const int* __restrict__ ei, const float* __restrict__ ef,
       const float* __restrict__ x,
       const float* __restrict__ pa, const float* __restrict__ pb,
       const float* __restrict__ w1,
       const float* __restrict__ w2, const float* __restrict__ b2,
       const float* __restrict__ xw1, const float* __restrict__ xb1,
       const float* __restrict__ xw2, const float* __restrict__ xb2,
       float* __restrict__ agg, float* __restrict__ cacc){
  int e = blockIdx.x*256+threadIdx.x;
  if (e>=NE) return;
  int s = ei[e], d = ei[NE+e];
  float dx = x[s*3+0]-x[d*3+0];
  float dy = x[s*3+1]-x[d*3+1];
  float dz = x[s*3+2]-x[d*3+2];
  float sq = dx*dx+dy*dy+dz*dz;
  float acc[64];
  const float4* pa4 = (const float4*)(pa + (size_t)s*64);
  const float4* pb4 = (const float4*)(pb + (size_t)d*64);
  #pragma unroll
  for(int q=0;q<16;q++){
    float4 A = pa4[q]; float4 B = pb4[q];
    acc[q*4+0]=A.x+B.x; acc[q*4+1]=A.y+B.y; acc[q*4+2]=A.z+B.z; acc[q*4+3]=A.w+B.w;
  }
  { const float* wr = w1 + 256*64;
    #pragma unroll
    for(int j=0;j<64;j++) acc[j] += sq*wr[j]; }
  { const float* efp = ef + (size_t)e*16;
    #pragma unroll
    for(int k=0;k<16;k++){
      float m = efp[k];
      const float* wr = w1 + (257+k)*64;
      #pragma unroll
      for(int j=0;j<64;j++) acc[j] += m*wr[j];
    } }
  float t[64];
  #pragma unroll
  for(int j=0;j<64;j++) t[j]=siluf(acc[j]);
  #pragma unroll
  for(int j=0;j<64;j++) acc[j]=b2[j];
  #pragma unroll
  for(int k=0;k<64;k++){
    const float* wr = w2 + k*64;
    float m = t[k];
    #pragma unroll
    for(int j=0;j<64;j++) acc[j] += m*wr[j];
  }
  #pragma unroll
  for(int j=0;j<64;j++) acc[j]=siluf(acc[j]);   // msg
  float* aggd = agg + (size_t)d*64;
  #pragma unroll
  for(int j=0;j<64;j++) atomicAdd(&aggd[j], acc[j]);
  // coordinate weight path: w = silu(msg@xw1+xb1)@xw2 + xb2
  #pragma unroll
  for(int j=0;j<64;j++) t[j]=xb1[j];
  #pragma unroll
  for(int k=0;k<64;k++){
    const float* wr = xw1 + k*64;
    float m = acc[k];
    #pragma unroll
    for(int j=0;j<64;j++) t[j] += m*wr[j];
  }
  float wv = xb2[0];
  #pragma unroll
  for(int k=0;k<64;k++) wv += siluf(t[k])*xw2[k];
  atomicAdd(&cacc[s*3+0], dx*wv);
  atomicAdd(&cacc[s*3+1], dy*wv);
  atomicAdd(&cacc[s*3+2], dz*wv);
}

// ---- node update: dh MLP + residual + LayerNorm + coord update ----
__global__ void k_node(const float* __restrict__ agg, const float* __restrict__ cacc,
                       const float* __restrict__ cntinv,
                       const float* __restrict__ hw1, const float* __restrict__ hb1,
                       const float* __restrict__ hw2, const float* __restrict__ hb2,
                       const float* __restrict__ lng, const float* __restrict__ lnb,
                       float* __restrict__ h, float* __restrict__ x){
  int wl=threadIdx.x>>6, lane=threadIdx.x&63;
  int n = blockIdx.x*4+wl;
  __shared__ float cat[4][192];
  __shared__ float t1[4][128];
  float ci = cntinv[n];
  float h0 = h[(size_t)n*128+2*lane], h1 = h[(size_t)n*128+2*lane+1];
  cat[wl][2*lane]=h0; cat[wl][2*lane+1]=h1;
  cat[wl][128+lane] = agg[(size_t)n*64+lane]*ci;
  __syncthreads();
  float a0=hb1[2*lane], a1=hb1[2*lane+1];
  for(int k=0;k<192;k++){
    float m = cat[wl][k];
    float2 w = ((const float2*)(hw1+k*128))[lane];
    a0 += m*w.x; a1 += m*w.y;
  }
  t1[wl][2*lane]=siluf(a0); t1[wl][2*lane+1]=siluf(a1);
  __syncthreads();
  float c0=hb2[2*lane], c1=hb2[2*lane+1];
  for(int k=0;k<128;k++){
    float m = t1[wl][k];
    float2 w = ((const float2*)(hw2+k*128))[lane];
    c0 += m*w.x; c1 += m*w.y;
  }
  float r0=h0+c0, r1=h1+c1;
  float sm=r0+r1, ss=r0*r0+r1*r1;
  #pragma unroll
  for(int off=32; off>0; off>>=1){
    sm += __shfl_xor(sm, off);
    ss += __shfl_xor(ss, off);
  }
  float mu = sm*(1.0f/128.0f);
  float var = ss*(1.0f/128.0f) - mu*mu;
  float rs = rsqrtf(fmaxf(var, 0.0f) + 1e-5f);
  float g0=lng[2*lane], g1=lng[2*lane+1], b0=lnb[2*lane], b1v=lnb[2*lane+1];
  h[(size_t)n*128+2*lane]   = (r0-mu)*rs*g0+b0;
  h[(size_t)n*128+2*lane+1] = (r1-mu)*rs*g1+b1v;
  if(lane<3) x[n*3+lane] += cacc[n*3+lane]*ci;
}

// ---- readout: graph mean (batch_idx sorted -> binary-search ranges) + 3-layer MLP ----
__device__ __forceinline__ int lowerb(const int* a, int n, int v){
  int lo=0, hi=n;
  while(lo<hi){ int mid=(lo+hi)>>1; if(a[mid]<v) lo=mid+1; else hi=mid; }
  return lo;
}

__global__ void k_readout(const int* __restrict__ batch, const float* __restrict__ h,
                          const float* __restrict__ w1, const float* __restrict__ b1,
                          const float* __restrict__ w2, const float* __restrict__ b2,
                          const float* __restrict__ w3, const float* __restrict__ b3,
                          float* __restrict__ out){
  int g = blockIdx.x;
  int wl = threadIdx.x>>6, lane = threadIdx.x&63;
  __shared__ float part[4][128];
  __shared__ float gh[128];
  __shared__ float r1[128];
  __shared__ float r2[64];
  int start = lowerb(batch, NN, g);
  int end   = lowerb(batch, NN, g+1);
  float s0=0.f, s1=0.f;
  for(int n=start+wl; n<end; n+=4){
    s0 += h[(size_t)n*128+2*lane];
    s1 += h[(size_t)n*128+2*lane+1];
  }
  part[wl][2*lane]=s0; part[wl][2*lane+1]=s1;
  __syncthreads();
  float ci = 1.0f/fmaxf((float)(end-start),1.0f);
  if(wl==0){
    gh[2*lane]   = (part[0][2*lane]+part[1][2*lane]+part[2][2*lane]+part[3][2*lane])*ci;
    gh[2*lane+1] = (part[0][2*lane+1]+part[1][2*lane+1]+part[2][2*lane+1]+part[3][2*lane+1])*ci;
  }
  __syncthreads();
  if(wl==0){
    float a0=b1[2*lane], a1=b1[2*lane+1];
    for(int k=0;k<128;k++){
      float m=gh[k];
      float2 w=((const float2*)(w1+k*128))[lane];
      a0+=m*w.x; a1+=m*w.y;
    }
    r1[2*lane]=siluf(a0); r1[2*lane+1]=siluf(a1);
  }
  __syncthreads();
  if(wl==0){
    float b=b2[lane];
    for(int k=0;k<128;k++) b += r1[k]*w2[k*64+lane];
    r2[lane]=siluf(b);
  }
  __syncthreads();
  if(wl==0 && lane<2){
    float o=b3[lane];
    for(int k=0;k<64;k++) o += r2[k]*w3[k*2+lane];
    out[g*2+lane]=o;
  }
}

extern "C" void kernel_launch(void* const* d_in, const int* in_sizes, int n_in,
                              void* d_out, int out_size, void* d_ws, size_t ws_size,
                              hipStream_t stream){
  const float* nf     = (const float*)d_in[0];
  const float* coords = (const float*)d_in[1];
  const int*   ei     = (const int*)d_in[2];
  const float* ef     = (const float*)d_in[3];
  const int*   batch  = (const int*)d_in[4];

  const float* enc_w1 = (const float*)d_in[5];
  const float* enc_b1 = (const float*)d_in[6];
  const float* enc_w2 = (const float*)d_in[7];
  const float* enc_b2 = (const float*)d_in[8];
  const float* pe_w1  = (const float*)d_in[9];
  const float* pe_b1  = (const float*)d_in[10];
  const float* pe_w2  = (const float*)d_in[11];
  const float* pe_b2  = (const float*)d_in[12];
  const float* ph_w1  = (const float*)d_in[13];
  const float* ph_b1  = (const float*)d_in[14];
  const float* ph_w2  = (const float*)d_in[15];
  const float* ph_b2  = (const float*)d_in[16];
  const float* px_w1  = (const float*)d_in[17];
  const float* px_b1  = (const float*)d_in[18];
  const float* px_w2  = (const float*)d_in[19];
  const float* px_b2  = (const float*)d_in[20];
  const float* ln_g   = (const float*)d_in[21];
  const float* ln_b   = (const float*)d_in[22];
  const float* ro_w1  = (const float*)d_in[23];
  const float* ro_b1  = (const float*)d_in[24];
  const float* ro_w2  = (const float*)d_in[25];
  const float* ro_b2  = (const float*)d_in[26];
  const float* ro_w3  = (const float*)d_in[27];
  const float* ro_b3  = (const float*)d_in[28];

  float* ws = (float*)d_ws;
  float* h      = ws;                          // NN*128
  float* x      = h    + (size_t)NN*128;       // NN*3
  float* agg    = x    + (size_t)NN*3;         // NN*64
  float* cacc   = agg  + (size_t)NN*64;        // NN*3   (contiguous after agg -> one memset)
  float* cntinv = cacc + (size_t)NN*3;         // NN
  float* pa     = cntinv + NN;                 // NN*64
  float* pb     = pa   + (size_t)NN*64;        // NN*64
  int*   cnt    = (int*)(pb + (size_t)NN*64);  // NN

  hipMemsetAsync(cnt, 0, NN*sizeof(int), stream);
  k_count<<<(NE+255)/256,256,0,stream>>>(ei, cnt);
  k_prep<<<(NN+255)/256,256,0,stream>>>(coords, cnt, x, cntinv);
  k_encoder<<<NN/4,256,0,stream>>>(nf, enc_w1, enc_b1, enc_w2, enc_b2, h);

  for(int l=0;l<NL;l++){
    hipMemsetAsync(agg, 0, (size_t)(NN*64+NN*3)*sizeof(float), stream);   // agg + cacc
    k_pre<<<NN/4,256,0,stream>>>(h, pe_w1+(size_t)l*273*64, pe_b1+l*64, pa, pb);
    k_edge<<<(NE+255)/256,256,0,stream>>>(ei, ef, x, pa, pb,
        pe_w1+(size_t)l*273*64,
        pe_w2+(size_t)l*64*64, pe_b2+l*64,
        px_w1+(size_t)l*64*64, px_b1+l*64,
        px_w2+l*64, px_b2+l,
        agg, cacc);
    k_node<<<NN/4,256,0,stream>>>(agg, cacc, cntinv,
        ph_w1+(size_t)l*192*128, ph_b1+l*128,
        ph_w2+(size_t)l*128*128, ph_b2+l*128,
        ln_g+l*128, ln_b+l*128, h, x);
  }

  k_readout<<<NG,256,0,stream>>>(batch, h,
      ro_w1, ro_b1, ro_w2, ro_b2, ro_w3, ro_b3, (float*)d_out);
}

// Round 3
// 9442.793 us; speedup vs baseline: 2.7176x; 2.7176x over previous
//
#include <hip/hip_runtime.h>
#include <hip/hip_bf16.h>

#define NN 50000
#define NE 1000000
#define NG 256
#define NL 6

__device__ __forceinline__ float siluf(float v){ return v / (1.0f + expf(-v)); }

// ---- degree counts (in-deg by dst, out-deg by src) ----
__global__ void k_degrees(const int* __restrict__ ei, int* __restrict__ cnt_dst,
                          int* __restrict__ cnt_src){
  int e = blockIdx.x*256 + threadIdx.x;
  if (e<NE){
    atomicAdd(&cnt_dst[ei[NE+e]], 1);
    atomicAdd(&cnt_src[ei[e]], 1);
  }
}

// ---- single-block exclusive scan of cnt[0..NN) -> roff[0..NN] ----
__global__ void k_scan(const int* __restrict__ cnt, int* __restrict__ roff){
  __shared__ int sdata[256];
  __shared__ int s_run;
  int t = threadIdx.x;
  if (t==0) s_run = 0;
  __syncthreads();
  for (int base=0; base<NN; base+=256){
    int i = base + t;
    int v = (i<NN) ? cnt[i] : 0;
    sdata[t] = v; __syncthreads();
    #pragma unroll
    for (int off=1; off<256; off<<=1){
      int xv = (t>=off) ? sdata[t-off] : 0;
      __syncthreads();
      sdata[t] += xv;
      __syncthreads();
    }
    int incl = sdata[t];
    if (i<NN) roff[i] = s_run + incl - v;
    __syncthreads();
    if (t==255) s_run += incl;
    __syncthreads();
  }
  if (t==0) roff[NN] = s_run;
}

// ---- scatter-fill CSR edge lists ----
__global__ void k_fill(const int* __restrict__ ei,
                       const int* __restrict__ roff_dst, const int* __restrict__ roff_src,
                       int* __restrict__ cur_dst, int* __restrict__ cur_src,
                       int* __restrict__ dlist, int* __restrict__ slist){
  int e = blockIdx.x*256 + threadIdx.x;
  if (e<NE){
    int d = ei[NE+e]; int p = atomicAdd(&cur_dst[d],1); dlist[roff_dst[d]+p] = e;
    int s = ei[e];    int q = atomicAdd(&cur_src[s],1); slist[roff_src[s]+q] = e;
  }
}

// ---- init coords f32 copy + 1/max(indeg,1) ----
__global__ void k_prep(const float* __restrict__ coords,
                       const int* __restrict__ cnt,
                       float* __restrict__ x, float* __restrict__ cntinv){
  int n = blockIdx.x*256+threadIdx.x;
  if (n<NN){
    x[n*3+0]=coords[n*3+0];
    x[n*3+1]=coords[n*3+1];
    x[n*3+2]=coords[n*3+2];
    cntinv[n]=1.0f/fmaxf((float)cnt[n],1.0f);
  }
}

// ---- encoder: h = silu(nf@w1+b1)@w2+b2 ; one wave per node, lane -> 2 outputs ----
__global__ void k_encoder(const float* __restrict__ nf,
                          const float* __restrict__ w1, const float* __restrict__ b1,
                          const float* __restrict__ w2, const float* __restrict__ b2,
                          float* __restrict__ h){
  int wl = threadIdx.x>>6, lane = threadIdx.x&63;
  int n = blockIdx.x*4 + wl;
  __shared__ float t1s[4][128];
  const float* nfp = nf + (size_t)n*16;
  float a0=b1[2*lane], a1=b1[2*lane+1];
  #pragma unroll
  for(int k=0;k<16;k++){
    float m = nfp[k];
    float2 w = ((const float2*)(w1+k*128))[lane];
    a0 += m*w.x; a1 += m*w.y;
  }
  t1s[wl][2*lane]=siluf(a0); t1s[wl][2*lane+1]=siluf(a1);
  __syncthreads();
  float c0=b2[2*lane], c1=b2[2*lane+1];
  for(int k=0;k<128;k++){
    float m = t1s[wl][k];
    float2 w = ((const float2*)(w2+k*128))[lane];
    c0 += m*w.x; c1 += m*w.y;
  }
  h[(size_t)n*128+2*lane]=c0; h[(size_t)n*128+2*lane+1]=c1;
}

// ---- per-layer node precompute: pa = b1 + h@W1[0:128], pb = h@W1[128:256] ----
__global__ void k_pre(const float* __restrict__ h,
                      const float* __restrict__ w1, const float* __restrict__ b1,
                      float* __restrict__ pa, float* __restrict__ pb){
  int wl = threadIdx.x>>6, lane = threadIdx.x&63;
  int n = blockIdx.x*4+wl;
  __shared__ float hs[4][128];
  hs[wl][2*lane]  =h[(size_t)n*128+2*lane];
  hs[wl][2*lane+1]=h[(size_t)n*128+2*lane+1];
  __syncthreads();
  float a=b1[lane], b=0.f;
  for(int k=0;k<128;k++){
    float m = hs[wl][k];
    a += m*w1[k*64+lane];
    b += m*w1[(128+k)*64+lane];
  }
  pa[(size_t)n*64+lane]=a; pb[(size_t)n*64+lane]=b;
}

// ---- phase A: thread per (dst-sorted) edge; write msg chunk + wv; NO atomics ----
__global__ void __launch_bounds__(256,1)
k_edgeA(const int* __restrict__ ei, const float* __restrict__ ef,
        const float* __restrict__ x,
        const float* __restrict__ pa, const float* __restrict__ pb,
        const int* __restrict__ roff_dst, const int* __restrict__ dlist,
        const float* __restrict__ w1,
        const float* __restrict__ w2, const float* __restrict__ b2,
        const float* __restrict__ xw1, const float* __restrict__ xb1,
        const float* __restrict__ xw2, const float* __restrict__ xb2,
        float* __restrict__ msgbuf, float* __restrict__ wv,
        int n0, int n1){
  int t = blockIdx.x*256+threadIdx.x;
  int base = roff_dst[n0];
  int endp = roff_dst[n1];
  int p = base + t;
  if (p >= endp) return;
  int e = dlist[p];
  int s = ei[e], d = ei[NE+e];
  float dx = x[s*3+0]-x[d*3+0];
  float dy = x[s*3+1]-x[d*3+1];
  float dz = x[s*3+2]-x[d*3+2];
  float sq = dx*dx+dy*dy+dz*dz;
  float acc[64];
  const float4* pa4 = (const float4*)(pa + (size_t)s*64);
  const float4* pb4 = (const float4*)(pb + (size_t)d*64);
  #pragma unroll
  for(int q=0;q<16;q++){
    float4 A = pa4[q]; float4 B = pb4[q];
    acc[q*4+0]=A.x+B.x; acc[q*4+1]=A.y+B.y; acc[q*4+2]=A.z+B.z; acc[q*4+3]=A.w+B.w;
  }
  { const float* wr = w1 + 256*64;
    #pragma unroll
    for(int j=0;j<64;j++) acc[j] += sq*wr[j]; }
  { const float4* efp = (const float4*)(ef + (size_t)e*16);
    #pragma unroll
    for(int k4=0;k4<4;k4++){
      float4 m4 = efp[k4];
      float mv[4] = {m4.x, m4.y, m4.z, m4.w};
      #pragma unroll
      for(int kk=0;kk<4;kk++){
        const float* wr = w1 + (257+k4*4+kk)*64;
        float m = mv[kk];
        #pragma unroll
        for(int j=0;j<64;j++) acc[j] += m*wr[j];
      }
    } }
  float tt[64];
  #pragma unroll
  for(int j=0;j<64;j++) tt[j]=siluf(acc[j]);
  #pragma unroll
  for(int j=0;j<64;j++) acc[j]=b2[j];
  #pragma unroll
  for(int k=0;k<64;k++){
    const float* wr = w2 + k*64;
    float m = tt[k];
    #pragma unroll
    for(int j=0;j<64;j++) acc[j] += m*wr[j];
  }
  #pragma unroll
  for(int j=0;j<64;j++) acc[j]=siluf(acc[j]);   // msg
  // store msg chunk (coalesced-ish float4)
  float4* mo = (float4*)(msgbuf + (size_t)t*64);
  #pragma unroll
  for(int q=0;q<16;q++){
    float4 v; v.x=acc[q*4+0]; v.y=acc[q*4+1]; v.z=acc[q*4+2]; v.w=acc[q*4+3];
    mo[q]=v;
  }
  // coordinate weight path: wv = silu(msg@xw1+xb1)@xw2 + xb2
  #pragma unroll
  for(int j=0;j<64;j++) tt[j]=xb1[j];
  #pragma unroll
  for(int k=0;k<64;k++){
    const float* wr = xw1 + k*64;
    float m = acc[k];
    #pragma unroll
    for(int j=0;j<64;j++) tt[j] += m*wr[j];
  }
  float wvv = xb2[0];
  #pragma unroll
  for(int k=0;k<64;k++) wvv += siluf(tt[k])*xw2[k];
  wv[e] = wvv;
}

// ---- phase B: wave per dst node; lane j sums msg over segment; pre-divide by count ----
__global__ void k_aggB(const float* __restrict__ msgbuf,
                       const int* __restrict__ roff_dst,
                       const float* __restrict__ cntinv,
                       float* __restrict__ agg, int n0, int n1){
  int wl = threadIdx.x>>6, lane = threadIdx.x&63;
  int n = n0 + blockIdx.x*4 + wl;
  if (n >= n1) return;
  int base = roff_dst[n0];
  int s = roff_dst[n], epos = roff_dst[n+1];
  float a = 0.f;
  for (int p=s; p<epos; p++) a += msgbuf[(size_t)(p-base)*64 + lane];
  agg[(size_t)n*64+lane] = a * cntinv[n];
}

// ---- phase C: wave per src node; sum diff*wv over out-edges; plain write ----
__global__ void k_coordC(const int* __restrict__ ei,
                         const int* __restrict__ roff_src, const int* __restrict__ slist,
                         const float* __restrict__ wv, const float* __restrict__ x,
                         float* __restrict__ cacc){
  int wl = threadIdx.x>>6, lane = threadIdx.x&63;
  int n = blockIdx.x*4 + wl;
  if (n >= NN) return;
  int s = roff_src[n], e2 = roff_src[n+1];
  float xs0=x[n*3+0], xs1=x[n*3+1], xs2=x[n*3+2];
  float a0=0.f, a1=0.f, a2=0.f;
  for (int p=s+lane; p<e2; p+=64){
    int e = slist[p];
    float w = wv[e];
    int d = ei[NE+e];
    a0 += (xs0 - x[d*3+0])*w;
    a1 += (xs1 - x[d*3+1])*w;
    a2 += (xs2 - x[d*3+2])*w;
  }
  #pragma unroll
  for(int off=32; off>0; off>>=1){
    a0 += __shfl_xor(a0, off);
    a1 += __shfl_xor(a1, off);
    a2 += __shfl_xor(a2, off);
  }
  if (lane==0){
    cacc[n*3+0]=a0; cacc[n*3+1]=a1; cacc[n*3+2]=a2;
  }
}

// ---- node update: dh MLP + residual + LayerNorm + coord update ----
__global__ void k_node(const float* __restrict__ agg, const float* __restrict__ cacc,
                       const float* __restrict__ cntinv,
                       const float* __restrict__ hw1, const float* __restrict__ hb1,
                       const float* __restrict__ hw2, const float* __restrict__ hb2,
                       const float* __restrict__ lng, const float* __restrict__ lnb,
                       float* __restrict__ h, float* __restrict__ x){
  int wl=threadIdx.x>>6, lane=threadIdx.x&63;
  int n = blockIdx.x*4+wl;
  __shared__ float cat[4][192];
  __shared__ float t1[4][128];
  float ci = cntinv[n];
  float h0 = h[(size_t)n*128+2*lane], h1 = h[(size_t)n*128+2*lane+1];
  cat[wl][2*lane]=h0; cat[wl][2*lane+1]=h1;
  cat[wl][128+lane] = agg[(size_t)n*64+lane];   // already divided by count
  __syncthreads();
  float a0=hb1[2*lane], a1=hb1[2*lane+1];
  for(int k=0;k<192;k++){
    float m = cat[wl][k];
    float2 w = ((const float2*)(hw1+k*128))[lane];
    a0 += m*w.x; a1 += m*w.y;
  }
  t1[wl][2*lane]=siluf(a0); t1[wl][2*lane+1]=siluf(a1);
  __syncthreads();
  float c0=hb2[2*lane], c1=hb2[2*lane+1];
  for(int k=0;k<128;k++){
    float m = t1[wl][k];
    float2 w = ((const float2*)(hw2+k*128))[lane];
    c0 += m*w.x; c1 += m*w.y;
  }
  float r0=h0+c0, r1=h1+c1;
  float sm=r0+r1, ss=r0*r0+r1*r1;
  #pragma unroll
  for(int off=32; off>0; off>>=1){
    sm += __shfl_xor(sm, off);
    ss += __shfl_xor(ss, off);
  }
  float mu = sm*(1.0f/128.0f);
  float var = ss*(1.0f/128.0f) - mu*mu;
  float rs = rsqrtf(fmaxf(var, 0.0f) + 1e-5f);
  float g0=lng[2*lane], g1=lng[2*lane+1], b0=lnb[2*lane], b1v=lnb[2*lane+1];
  h[(size_t)n*128+2*lane]   = (r0-mu)*rs*g0+b0;
  h[(size_t)n*128+2*lane+1] = (r1-mu)*rs*g1+b1v;
  if(lane<3) x[n*3+lane] += cacc[n*3+lane]*ci;
}

// ---- readout ----
__device__ __forceinline__ int lowerb(const int* a, int n, int v){
  int lo=0, hi=n;
  while(lo<hi){ int mid=(lo+hi)>>1; if(a[mid]<v) lo=mid+1; else hi=mid; }
  return lo;
}

__global__ void k_readout(const int* __restrict__ batch, const float* __restrict__ h,
                          const float* __restrict__ w1, const float* __restrict__ b1,
                          const float* __restrict__ w2, const float* __restrict__ b2,
                          const float* __restrict__ w3, const float* __restrict__ b3,
                          float* __restrict__ out){
  int g = blockIdx.x;
  int wl = threadIdx.x>>6, lane = threadIdx.x&63;
  __shared__ float part[4][128];
  __shared__ float gh[128];
  __shared__ float r1[128];
  __shared__ float r2[64];
  int start = lowerb(batch, NN, g);
  int end   = lowerb(batch, NN, g+1);
  float s0=0.f, s1=0.f;
  for(int n=start+wl; n<end; n+=4){
    s0 += h[(size_t)n*128+2*lane];
    s1 += h[(size_t)n*128+2*lane+1];
  }
  part[wl][2*lane]=s0; part[wl][2*lane+1]=s1;
  __syncthreads();
  float ci = 1.0f/fmaxf((float)(end-start),1.0f);
  if(wl==0){
    gh[2*lane]   = (part[0][2*lane]+part[1][2*lane]+part[2][2*lane]+part[3][2*lane])*ci;
    gh[2*lane+1] = (part[0][2*lane+1]+part[1][2*lane+1]+part[2][2*lane+1]+part[3][2*lane+1])*ci;
  }
  __syncthreads();
  if(wl==0){
    float a0=b1[2*lane], a1=b1[2*lane+1];
    for(int k=0;k<128;k++){
      float m=gh[k];
      float2 w=((const float2*)(w1+k*128))[lane];
      a0+=m*w.x; a1+=m*w.y;
    }
    r1[2*lane]=siluf(a0); r1[2*lane+1]=siluf(a1);
  }
  __syncthreads();
  if(wl==0){
    float b=b2[lane];
    for(int k=0;k<128;k++) b += r1[k]*w2[k*64+lane];
    r2[lane]=siluf(b);
  }
  __syncthreads();
  if(wl==0 && lane<2){
    float o=b3[lane];
    for(int k=0;k<64;k++) o += r2[k]*w3[k*2+lane];
    out[g*2+lane]=o;
  }
}

extern "C" void kernel_launch(void* const* d_in, const int* in_sizes, int n_in,
                              void* d_out, int out_size, void* d_ws, size_t ws_size,
                              hipStream_t stream){
  const float* nf     = (const float*)d_in[0];
  const float* coords = (const float*)d_in[1];
  const int*   ei     = (const int*)d_in[2];
  const float* ef     = (const float*)d_in[3];
  const int*   batch  = (const int*)d_in[4];

  const float* enc_w1 = (const float*)d_in[5];
  const float* enc_b1 = (const float*)d_in[6];
  const float* enc_w2 = (const float*)d_in[7];
  const float* enc_b2 = (const float*)d_in[8];
  const float* pe_w1  = (const float*)d_in[9];
  const float* pe_b1  = (const float*)d_in[10];
  const float* pe_w2  = (const float*)d_in[11];
  const float* pe_b2  = (const float*)d_in[12];
  const float* ph_w1  = (const float*)d_in[13];
  const float* ph_b1  = (const float*)d_in[14];
  const float* ph_w2  = (const float*)d_in[15];
  const float* ph_b2  = (const float*)d_in[16];
  const float* px_w1  = (const float*)d_in[17];
  const float* px_b1  = (const float*)d_in[18];
  const float* px_w2  = (const float*)d_in[19];
  const float* px_b2  = (const float*)d_in[20];
  const float* ln_g   = (const float*)d_in[21];
  const float* ln_b   = (const float*)d_in[22];
  const float* ro_w1  = (const float*)d_in[23];
  const float* ro_b1  = (const float*)d_in[24];
  const float* ro_w2  = (const float*)d_in[25];
  const float* ro_b2  = (const float*)d_in[26];
  const float* ro_w3  = (const float*)d_in[27];
  const float* ro_b3  = (const float*)d_in[28];

  char* wsb = (char*)d_ws;
  size_t off = 0;
  auto alloc_f = [&](size_t nfl)->float*{ float* p=(float*)(wsb+off); off+=nfl*4; return p; };
  auto alloc_i = [&](size_t nin)->int*  { int*   p=(int*)(wsb+off);   off+=nin*4; return p; };

  float* h      = alloc_f((size_t)NN*128);
  float* x      = alloc_f((size_t)NN*3);
  float* agg    = alloc_f((size_t)NN*64);
  float* cacc   = alloc_f((size_t)NN*3);
  float* cntinv = alloc_f(NN);
  float* pa     = alloc_f((size_t)NN*64);
  float* pb     = alloc_f((size_t)NN*64);
  float* wv     = alloc_f(NE);
  int* roff_dst = alloc_i(NN+1);
  int* roff_src = alloc_i(NN+1);
  int* dlist    = alloc_i(NE);
  int* slist    = alloc_i(NE);
  int* cnt_dst  = alloc_i(NN);   // cnt_dst..cur_src contiguous -> one memset
  int* cnt_src  = alloc_i(NN);
  int* cur_dst  = alloc_i(NN);
  int* cur_src  = alloc_i(NN);
  size_t base_bytes = off;
  float* msgbuf = (float*)(wsb + off);
  size_t cap_edges = (ws_size > base_bytes) ? (ws_size - base_bytes) / 256 : 0;

  // pick chunk count (power of 2) so expected chunk edges + slack fit in cap
  int nchunks = 1;
  while (nchunks < 64 && (size_t)(NE/nchunks + 60000) > cap_edges) nchunks <<= 1;
  size_t chunk_cap = (size_t)NE/nchunks + 60000;
  if (chunk_cap > cap_edges) chunk_cap = cap_edges;
  int chunk_nodes = (NN + nchunks - 1) / nchunks;
  int gridA = (int)((chunk_cap + 255) / 256);

  hipMemsetAsync(cnt_dst, 0, (size_t)4*NN*sizeof(int), stream);
  k_degrees<<<(NE+255)/256,256,0,stream>>>(ei, cnt_dst, cnt_src);
  k_scan<<<1,256,0,stream>>>(cnt_dst, roff_dst);
  k_scan<<<1,256,0,stream>>>(cnt_src, roff_src);
  k_fill<<<(NE+255)/256,256,0,stream>>>(ei, roff_dst, roff_src, cur_dst, cur_src, dlist, slist);
  k_prep<<<(NN+255)/256,256,0,stream>>>(coords, cnt_dst, x, cntinv);
  k_encoder<<<NN/4,256,0,stream>>>(nf, enc_w1, enc_b1, enc_w2, enc_b2, h);

  for(int l=0;l<NL;l++){
    k_pre<<<NN/4,256,0,stream>>>(h, pe_w1+(size_t)l*273*64, pe_b1+l*64, pa, pb);
    for(int c=0;c<nchunks;c++){
      int n0 = c*chunk_nodes;
      int n1 = n0 + chunk_nodes; if (n1 > NN) n1 = NN;
      if (n0 >= NN) break;
      k_edgeA<<<gridA,256,0,stream>>>(ei, ef, x, pa, pb, roff_dst, dlist,
          pe_w1+(size_t)l*273*64,
          pe_w2+(size_t)l*64*64, pe_b2+l*64,
          px_w1+(size_t)l*64*64, px_b1+l*64,
          px_w2+l*64, px_b2+l,
          msgbuf, wv, n0, n1);
      k_aggB<<<(chunk_nodes+3)/4,256,0,stream>>>(msgbuf, roff_dst, cntinv, agg, n0, n1);
    }
    k_coordC<<<(NN+3)/4,256,0,stream>>>(ei, roff_src, slist, wv, x, cacc);
    k_node<<<NN/4,256,0,stream>>>(agg, cacc, cntinv,
        ph_w1+(size_t)l*192*128, ph_b1+l*128,
        ph_w2+(size_t)l*128*128, ph_b2+l*128,
        ln_g+l*128, ln_b+l*128, h, x);
  }

  k_readout<<<NG,256,0,stream>>>(batch, h,
      ro_w1, ro_b1, ro_w2, ro_b2, ro_w3, ro_b3, (float*)d_out);
}

// Round 4
// 6622.124 us; speedup vs baseline: 3.8752x; 1.4259x over previous
//
#include <hip/hip_runtime.h>
#include <hip/hip_bf16.h>

#define NN 50000
#define NE 1000000
#define NG 256
#define NL 6
#define NB_SCAN 196   // ceil(NN/256)

__device__ __forceinline__ float siluf(float v){ return v / (1.0f + expf(-v)); }

// ---- degree counts ----
__global__ void k_degrees(const int* __restrict__ ei, int* __restrict__ cnt_dst,
                          int* __restrict__ cnt_src){
  int e = blockIdx.x*256 + threadIdx.x;
  if (e<NE){
    atomicAdd(&cnt_dst[ei[NE+e]], 1);
    atomicAdd(&cnt_src[ei[e]], 1);
  }
}

// ---- hierarchical scan: stage 1 (per-block exclusive + block sums) ----
__global__ void k_scan1(const int* __restrict__ cnt, int* __restrict__ roff,
                        int* __restrict__ bsum){
  __shared__ int sd[256];
  int t=threadIdx.x; int i=blockIdx.x*256+t;
  int v=(i<NN)?cnt[i]:0;
  sd[t]=v; __syncthreads();
  #pragma unroll
  for(int off=1;off<256;off<<=1){
    int xv=(t>=off)?sd[t-off]:0; __syncthreads();
    sd[t]+=xv; __syncthreads();
  }
  if(i<NN) roff[i]=sd[t]-v;
  if(t==255) bsum[blockIdx.x]=sd[t];
}
// ---- stage 2: scan block sums (single small block) ----
__global__ void k_scan2(const int* __restrict__ bsum, int* __restrict__ bbase,
                        int* __restrict__ roff){
  __shared__ int sd[256];
  int t=threadIdx.x;
  int v=(t<NB_SCAN)?bsum[t]:0;
  sd[t]=v; __syncthreads();
  #pragma unroll
  for(int off=1;off<256;off<<=1){
    int xv=(t>=off)?sd[t-off]:0; __syncthreads();
    sd[t]+=xv; __syncthreads();
  }
  if(t<NB_SCAN) bbase[t]=sd[t]-v;
  if(t==255) roff[NN]=sd[t];
}
// ---- stage 3: add block bases ----
__global__ void k_scan3(int* __restrict__ roff, const int* __restrict__ bbase){
  int i=blockIdx.x*256+threadIdx.x;
  if(i<NN) roff[i]+=bbase[blockIdx.x];
}

// ---- scatter-fill CSR edge lists ----
__global__ void k_fill(const int* __restrict__ ei,
                       const int* __restrict__ roff_dst, const int* __restrict__ roff_src,
                       int* __restrict__ cur_dst, int* __restrict__ cur_src,
                       int* __restrict__ dlist, int* __restrict__ slist){
  int e = blockIdx.x*256 + threadIdx.x;
  if (e<NE){
    int d = ei[NE+e]; int p = atomicAdd(&cur_dst[d],1); dlist[roff_dst[d]+p] = e;
    int s = ei[e];    int q = atomicAdd(&cur_src[s],1); slist[roff_src[s]+q] = e;
  }
}

// ---- init coords + 1/max(indeg,1) ----
__global__ void k_prep(const float* __restrict__ coords,
                       const int* __restrict__ cnt,
                       float* __restrict__ x, float* __restrict__ cntinv){
  int n = blockIdx.x*256+threadIdx.x;
  if (n<NN){
    x[n*3+0]=coords[n*3+0];
    x[n*3+1]=coords[n*3+1];
    x[n*3+2]=coords[n*3+2];
    cntinv[n]=1.0f/fmaxf((float)cnt[n],1.0f);
  }
}

// ==== tiled encoder: 32 nodes/block, h = silu(nf@w1+b1)@w2+b2 ====
__global__ void __launch_bounds__(256)
k_encoder(const float* __restrict__ nf,
          const float* __restrict__ w1, const float* __restrict__ b1,
          const float* __restrict__ w2, const float* __restrict__ b2,
          float* __restrict__ h){
  __shared__ float in1[32][17];
  __shared__ float t1[32][129];
  __shared__ float wt[16][136];
  int tid=threadIdx.x;
  int g0=blockIdx.x*32;
  int ty=tid>>4, tx=tid&15;
  int n0=ty*2, n1=ty*2+1;
  // load inputs (clamp OOB node for loads; stores guarded)
  { int n=tid>>3, c=(tid&7)*2;
    int gn=g0+n; if(gn>=NN) gn=NN-1;
    float2 v=*(const float2*)(nf+(size_t)gn*16+c);
    in1[n][c]=v.x; in1[n][c+1]=v.y; }
  // stage w1 (16x128) fully
  { int c=tx*8;
    const float* src=w1+(size_t)ty*128+c;
    *(float4*)&wt[ty][c]  =*(const float4*)src;
    *(float4*)&wt[ty][c+4]=*(const float4*)(src+4); }
  __syncthreads();
  float4 a00,a01,a10,a11;
  a00=*(const float4*)(b1+tx*8); a01=*(const float4*)(b1+tx*8+4);
  a10=a00; a11=a01;
  #pragma unroll
  for(int k=0;k<16;k++){
    float m0=in1[n0][k], m1=in1[n1][k];
    float4 wa=*(float4*)&wt[k][tx*8], wb=*(float4*)&wt[k][tx*8+4];
    a00.x+=m0*wa.x; a00.y+=m0*wa.y; a00.z+=m0*wa.z; a00.w+=m0*wa.w;
    a01.x+=m0*wb.x; a01.y+=m0*wb.y; a01.z+=m0*wb.z; a01.w+=m0*wb.w;
    a10.x+=m1*wa.x; a10.y+=m1*wa.y; a10.z+=m1*wa.z; a10.w+=m1*wa.w;
    a11.x+=m1*wb.x; a11.y+=m1*wb.y; a11.z+=m1*wb.z; a11.w+=m1*wb.w;
  }
  int c8=tx*8;
  t1[n0][c8+0]=siluf(a00.x); t1[n0][c8+1]=siluf(a00.y); t1[n0][c8+2]=siluf(a00.z); t1[n0][c8+3]=siluf(a00.w);
  t1[n0][c8+4]=siluf(a01.x); t1[n0][c8+5]=siluf(a01.y); t1[n0][c8+6]=siluf(a01.z); t1[n0][c8+7]=siluf(a01.w);
  t1[n1][c8+0]=siluf(a10.x); t1[n1][c8+1]=siluf(a10.y); t1[n1][c8+2]=siluf(a10.z); t1[n1][c8+3]=siluf(a10.w);
  t1[n1][c8+4]=siluf(a11.x); t1[n1][c8+5]=siluf(a11.y); t1[n1][c8+6]=siluf(a11.z); t1[n1][c8+7]=siluf(a11.w);
  __syncthreads();
  // GEMM2: t1(32x128) @ w2(128x128)
  a00=*(const float4*)(b2+c8); a01=*(const float4*)(b2+c8+4);
  a10=a00; a11=a01;
  for(int kt=0;kt<8;kt++){
    { const float* src=w2+(size_t)(kt*16+ty)*128+c8;
      *(float4*)&wt[ty][c8]  =*(const float4*)src;
      *(float4*)&wt[ty][c8+4]=*(const float4*)(src+4); }
    __syncthreads();
    #pragma unroll
    for(int kk=0;kk<16;kk++){
      int k=kt*16+kk;
      float m0=t1[n0][k], m1=t1[n1][k];
      float4 wa=*(float4*)&wt[kk][c8], wb=*(float4*)&wt[kk][c8+4];
      a00.x+=m0*wa.x; a00.y+=m0*wa.y; a00.z+=m0*wa.z; a00.w+=m0*wa.w;
      a01.x+=m0*wb.x; a01.y+=m0*wb.y; a01.z+=m0*wb.z; a01.w+=m0*wb.w;
      a10.x+=m1*wa.x; a10.y+=m1*wa.y; a10.z+=m1*wa.z; a10.w+=m1*wa.w;
      a11.x+=m1*wb.x; a11.y+=m1*wb.y; a11.z+=m1*wb.z; a11.w+=m1*wb.w;
    }
    __syncthreads();
  }
  int gn0=g0+n0, gn1=g0+n1;
  if(gn0<NN){ *(float4*)(h+(size_t)gn0*128+c8)=a00; *(float4*)(h+(size_t)gn0*128+c8+4)=a01; }
  if(gn1<NN){ *(float4*)(h+(size_t)gn1*128+c8)=a10; *(float4*)(h+(size_t)gn1*128+c8+4)=a11; }
}

// ==== tiled k_pre: out[n][0:64]=pa=b1+h@W[0:128], out[n][64:128]=pb=h@W[128:256] ====
__global__ void __launch_bounds__(256)
k_pre(const float* __restrict__ h,
      const float* __restrict__ w1, const float* __restrict__ b1,
      float* __restrict__ pa, float* __restrict__ pb){
  __shared__ float hs[32][129];
  __shared__ float wt[16][136];
  int tid=threadIdx.x;
  int g0=blockIdx.x*32;
  int ty=tid>>4, tx=tid&15;
  int n0=ty*2, n1=ty*2+1;
  // load hs
  { int n=tid>>3, c0=(tid&7)*16;
    int gn=g0+n; if(gn>=NN) gn=NN-1;
    const float* src=h+(size_t)gn*128+c0;
    #pragma unroll
    for(int q=0;q<4;q++){
      float4 v=*(const float4*)(src+q*4);
      hs[n][c0+q*4]=v.x; hs[n][c0+q*4+1]=v.y; hs[n][c0+q*4+2]=v.z; hs[n][c0+q*4+3]=v.w;
    } }
  int c8=tx*8;
  float4 a00,a01,a10,a11;
  if(tx<8){ a00=*(const float4*)(b1+c8); a01=*(const float4*)(b1+c8+4); }
  else    { a00=make_float4(0,0,0,0); a01=a00; }
  a10=a00; a11=a01;
  for(int kt=0;kt<8;kt++){
    { int grow=(tx<8)?(kt*16+ty):(128+kt*16+ty);
      int gcol=(tx&7)*8;
      const float* src=w1+(size_t)grow*64+gcol;
      *(float4*)&wt[ty][c8]  =*(const float4*)src;
      *(float4*)&wt[ty][c8+4]=*(const float4*)(src+4); }
    __syncthreads();
    #pragma unroll
    for(int kk=0;kk<16;kk++){
      int k=kt*16+kk;
      float m0=hs[n0][k], m1=hs[n1][k];
      float4 wa=*(float4*)&wt[kk][c8], wb=*(float4*)&wt[kk][c8+4];
      a00.x+=m0*wa.x; a00.y+=m0*wa.y; a00.z+=m0*wa.z; a00.w+=m0*wa.w;
      a01.x+=m0*wb.x; a01.y+=m0*wb.y; a01.z+=m0*wb.z; a01.w+=m0*wb.w;
      a10.x+=m1*wa.x; a10.y+=m1*wa.y; a10.z+=m1*wa.z; a10.w+=m1*wa.w;
      a11.x+=m1*wb.x; a11.y+=m1*wb.y; a11.z+=m1*wb.z; a11.w+=m1*wb.w;
    }
    __syncthreads();
  }
  int gn0=g0+n0, gn1=g0+n1;
  float* base0 = (tx<8)? (pa+(size_t)gn0*64+c8) : (pb+(size_t)gn0*64+(c8-64));
  float* base1 = (tx<8)? (pa+(size_t)gn1*64+c8) : (pb+(size_t)gn1*64+(c8-64));
  if(gn0<NN){ *(float4*)base0=a00; *(float4*)(base0+4)=a01; }
  if(gn1<NN){ *(float4*)base1=a10; *(float4*)(base1+4)=a11; }
}

// ---- phase A: thread per (dst-sorted) edge; write msg chunk + wv ----
__global__ void __launch_bounds__(256,1)
k_edgeA(const int* __restrict__ ei, const float* __restrict__ ef,
        const float* __restrict__ x,
        const float* __restrict__ pa, const float* __restrict__ pb,
        const int* __restrict__ roff_dst, const int* __restrict__ dlist,
        const float* __restrict__ w1,
        const float* __restrict__ w2, const float* __restrict__ b2,
        const float* __restrict__ xw1, const float* __restrict__ xb1,
        const float* __restrict__ xw2, const float* __restrict__ xb2,
        float* __restrict__ msgbuf, float* __restrict__ wv,
        int n0, int n1){
  int t = blockIdx.x*256+threadIdx.x;
  int base = roff_dst[n0];
  int endp = roff_dst[n1];
  int p = base + t;
  if (p >= endp) return;
  int e = dlist[p];
  int s = ei[e], d = ei[NE+e];
  float dx = x[s*3+0]-x[d*3+0];
  float dy = x[s*3+1]-x[d*3+1];
  float dz = x[s*3+2]-x[d*3+2];
  float sq = dx*dx+dy*dy+dz*dz;
  float acc[64];
  const float4* pa4 = (const float4*)(pa + (size_t)s*64);
  const float4* pb4 = (const float4*)(pb + (size_t)d*64);
  #pragma unroll
  for(int q=0;q<16;q++){
    float4 A = pa4[q]; float4 B = pb4[q];
    acc[q*4+0]=A.x+B.x; acc[q*4+1]=A.y+B.y; acc[q*4+2]=A.z+B.z; acc[q*4+3]=A.w+B.w;
  }
  { const float* wr = w1 + 256*64;
    #pragma unroll
    for(int j=0;j<64;j++) acc[j] += sq*wr[j]; }
  { const float4* efp = (const float4*)(ef + (size_t)e*16);
    #pragma unroll
    for(int k4=0;k4<4;k4++){
      float4 m4 = efp[k4];
      float mv[4] = {m4.x, m4.y, m4.z, m4.w};
      #pragma unroll
      for(int kk=0;kk<4;kk++){
        const float* wr = w1 + (257+k4*4+kk)*64;
        float m = mv[kk];
        #pragma unroll
        for(int j=0;j<64;j++) acc[j] += m*wr[j];
      }
    } }
  float tt[64];
  #pragma unroll
  for(int j=0;j<64;j++) tt[j]=siluf(acc[j]);
  #pragma unroll
  for(int j=0;j<64;j++) acc[j]=b2[j];
  #pragma unroll
  for(int k=0;k<64;k++){
    const float* wr = w2 + k*64;
    float m = tt[k];
    #pragma unroll
    for(int j=0;j<64;j++) acc[j] += m*wr[j];
  }
  #pragma unroll
  for(int j=0;j<64;j++) acc[j]=siluf(acc[j]);   // msg
  float4* mo = (float4*)(msgbuf + (size_t)t*64);
  #pragma unroll
  for(int q=0;q<16;q++){
    float4 v; v.x=acc[q*4+0]; v.y=acc[q*4+1]; v.z=acc[q*4+2]; v.w=acc[q*4+3];
    mo[q]=v;
  }
  #pragma unroll
  for(int j=0;j<64;j++) tt[j]=xb1[j];
  #pragma unroll
  for(int k=0;k<64;k++){
    const float* wr = xw1 + k*64;
    float m = acc[k];
    #pragma unroll
    for(int j=0;j<64;j++) tt[j] += m*wr[j];
  }
  float wvv = xb2[0];
  #pragma unroll
  for(int k=0;k<64;k++) wvv += siluf(tt[k])*xw2[k];
  wv[e] = wvv;
}

// ---- phase B: wave per dst node; pre-divide by count ----
__global__ void k_aggB(const float* __restrict__ msgbuf,
                       const int* __restrict__ roff_dst,
                       const float* __restrict__ cntinv,
                       float* __restrict__ agg, int n0, int n1){
  int wl = threadIdx.x>>6, lane = threadIdx.x&63;
  int n = n0 + blockIdx.x*4 + wl;
  if (n >= n1) return;
  int base = roff_dst[n0];
  int s = roff_dst[n], epos = roff_dst[n+1];
  float a = 0.f;
  for (int p=s; p<epos; p++) a += msgbuf[(size_t)(p-base)*64 + lane];
  agg[(size_t)n*64+lane] = a * cntinv[n];
}

// ---- phase C: 16 lanes per src node ----
__global__ void k_coordC(const int* __restrict__ ei,
                         const int* __restrict__ roff_src, const int* __restrict__ slist,
                         const float* __restrict__ wv, const float* __restrict__ x,
                         float* __restrict__ cacc){
  int tid=threadIdx.x;
  int grp=tid>>4, sub=tid&15;
  int n = blockIdx.x*16 + grp;
  if (n >= NN) return;
  int s = roff_src[n], e2 = roff_src[n+1];
  float xs0=x[n*3+0], xs1=x[n*3+1], xs2=x[n*3+2];
  float a0=0.f, a1=0.f, a2=0.f;
  for (int p=s+sub; p<e2; p+=16){
    int e = slist[p];
    float w = wv[e];
    int d = ei[NE+e];
    a0 += (xs0 - x[d*3+0])*w;
    a1 += (xs1 - x[d*3+1])*w;
    a2 += (xs2 - x[d*3+2])*w;
  }
  #pragma unroll
  for(int off=1; off<16; off<<=1){
    a0 += __shfl_xor(a0, off);
    a1 += __shfl_xor(a1, off);
    a2 += __shfl_xor(a2, off);
  }
  if (sub==0){
    cacc[n*3+0]=a0; cacc[n*3+1]=a1; cacc[n*3+2]=a2;
  }
}

// ==== tiled k_node: dh MLP + residual + LayerNorm + coord update ====
__global__ void __launch_bounds__(256)
k_node(const float* __restrict__ agg, const float* __restrict__ cacc,
       const float* __restrict__ cntinv,
       const float* __restrict__ hw1, const float* __restrict__ hb1,
       const float* __restrict__ hw2, const float* __restrict__ hb2,
       const float* __restrict__ lng, const float* __restrict__ lnb,
       float* __restrict__ h, float* __restrict__ x){
  __shared__ float cat[32][193];
  __shared__ float t1[32][129];
  __shared__ float wt[16][136];
  __shared__ float psA[32][8], psB[32][8];
  __shared__ float mu_s[32], rs_s[32];
  int tid=threadIdx.x;
  int g0=blockIdx.x*32;
  int ty=tid>>4, tx=tid&15;
  int n0=ty*2, n1=ty*2+1;
  int c8=tx*8;
  // load cat = [h | agg]
  { int n=tid>>3, c0=(tid&7)*16;
    int gn=g0+n; if(gn>=NN) gn=NN-1;
    const float* src=h+(size_t)gn*128+c0;
    #pragma unroll
    for(int q=0;q<4;q++){
      float4 v=*(const float4*)(src+q*4);
      cat[n][c0+q*4]=v.x; cat[n][c0+q*4+1]=v.y; cat[n][c0+q*4+2]=v.z; cat[n][c0+q*4+3]=v.w;
    }
    int ca=(tid&7)*8;
    const float* srca=agg+(size_t)gn*64+ca;
    #pragma unroll
    for(int q=0;q<2;q++){
      float4 v=*(const float4*)(srca+q*4);
      cat[n][128+ca+q*4]=v.x; cat[n][128+ca+q*4+1]=v.y; cat[n][128+ca+q*4+2]=v.z; cat[n][128+ca+q*4+3]=v.w;
    } }
  float4 a00=*(const float4*)(hb1+c8), a01=*(const float4*)(hb1+c8+4);
  float4 a10=a00, a11=a01;
  // GEMM1: cat(32x192) @ hw1(192x128)
  for(int kt=0;kt<12;kt++){
    { const float* src=hw1+(size_t)(kt*16+ty)*128+c8;
      *(float4*)&wt[ty][c8]  =*(const float4*)src;
      *(float4*)&wt[ty][c8+4]=*(const float4*)(src+4); }
    __syncthreads();
    #pragma unroll
    for(int kk=0;kk<16;kk++){
      int k=kt*16+kk;
      float m0=cat[n0][k], m1=cat[n1][k];
      float4 wa=*(float4*)&wt[kk][c8], wb=*(float4*)&wt[kk][c8+4];
      a00.x+=m0*wa.x; a00.y+=m0*wa.y; a00.z+=m0*wa.z; a00.w+=m0*wa.w;
      a01.x+=m0*wb.x; a01.y+=m0*wb.y; a01.z+=m0*wb.z; a01.w+=m0*wb.w;
      a10.x+=m1*wa.x; a10.y+=m1*wa.y; a10.z+=m1*wa.z; a10.w+=m1*wa.w;
      a11.x+=m1*wb.x; a11.y+=m1*wb.y; a11.z+=m1*wb.z; a11.w+=m1*wb.w;
    }
    __syncthreads();
  }
  t1[n0][c8+0]=siluf(a00.x); t1[n0][c8+1]=siluf(a00.y); t1[n0][c8+2]=siluf(a00.z); t1[n0][c8+3]=siluf(a00.w);
  t1[n0][c8+4]=siluf(a01.x); t1[n0][c8+5]=siluf(a01.y); t1[n0][c8+6]=siluf(a01.z); t1[n0][c8+7]=siluf(a01.w);
  t1[n1][c8+0]=siluf(a10.x); t1[n1][c8+1]=siluf(a10.y); t1[n1][c8+2]=siluf(a10.z); t1[n1][c8+3]=siluf(a10.w);
  t1[n1][c8+4]=siluf(a11.x); t1[n1][c8+5]=siluf(a11.y); t1[n1][c8+6]=siluf(a11.z); t1[n1][c8+7]=siluf(a11.w);
  __syncthreads();
  // GEMM2: t1(32x128) @ hw2(128x128)
  a00=*(const float4*)(hb2+c8); a01=*(const float4*)(hb2+c8+4);
  a10=a00; a11=a01;
  for(int kt=0;kt<8;kt++){
    { const float* src=hw2+(size_t)(kt*16+ty)*128+c8;
      *(float4*)&wt[ty][c8]  =*(const float4*)src;
      *(float4*)&wt[ty][c8+4]=*(const float4*)(src+4); }
    __syncthreads();
    #pragma unroll
    for(int kk=0;kk<16;kk++){
      int k=kt*16+kk;
      float m0=t1[n0][k], m1=t1[n1][k];
      float4 wa=*(float4*)&wt[kk][c8], wb=*(float4*)&wt[kk][c8+4];
      a00.x+=m0*wa.x; a00.y+=m0*wa.y; a00.z+=m0*wa.z; a00.w+=m0*wa.w;
      a01.x+=m0*wb.x; a01.y+=m0*wb.y; a01.z+=m0*wb.z; a01.w+=m0*wb.w;
      a10.x+=m1*wa.x; a10.y+=m1*wa.y; a10.z+=m1*wa.z; a10.w+=m1*wa.w;
      a11.x+=m1*wb.x; a11.y+=m1*wb.y; a11.z+=m1*wb.z; a11.w+=m1*wb.w;
    }
    __syncthreads();
  }
  // residual: r = h + dh, store into cat[n][c] (own cells only)
  cat[n0][c8+0]+=a00.x; cat[n0][c8+1]+=a00.y; cat[n0][c8+2]+=a00.z; cat[n0][c8+3]+=a00.w;
  cat[n0][c8+4]+=a01.x; cat[n0][c8+5]+=a01.y; cat[n0][c8+6]+=a01.z; cat[n0][c8+7]+=a01.w;
  cat[n1][c8+0]+=a10.x; cat[n1][c8+1]+=a10.y; cat[n1][c8+2]+=a10.z; cat[n1][c8+3]+=a10.w;
  cat[n1][c8+4]+=a11.x; cat[n1][c8+5]+=a11.y; cat[n1][c8+6]+=a11.z; cat[n1][c8+7]+=a11.w;
  __syncthreads();
  // LayerNorm: 8 threads per row
  { int rid=tid>>3, sub=tid&7;
    float sm=0.f, ss=0.f;
    #pragma unroll
    for(int i=0;i<16;i++){ float v=cat[rid][sub*16+i]; sm+=v; ss+=v*v; }
    psA[rid][sub]=sm; psB[rid][sub]=ss; }
  __syncthreads();
  { int rid=tid>>3, sub=tid&7;
    if(sub==0){
      float sm=0.f, ss=0.f;
      #pragma unroll
      for(int i=0;i<8;i++){ sm+=psA[rid][i]; ss+=psB[rid][i]; }
      float mu=sm*(1.0f/128.0f);
      float var=ss*(1.0f/128.0f)-mu*mu;
      mu_s[rid]=mu; rs_s[rid]=rsqrtf(fmaxf(var,0.0f)+1e-5f);
    } }
  __syncthreads();
  { int rid=tid>>3, sub=tid&7;
    int gn=g0+rid;
    if(gn<NN){
      float mu=mu_s[rid], rs=rs_s[rid];
      int c0=sub*16;
      #pragma unroll
      for(int q=0;q<4;q++){
        float4 g4=*(const float4*)(lng+c0+q*4);
        float4 b4=*(const float4*)(lnb+c0+q*4);
        float4 o;
        o.x=(cat[rid][c0+q*4+0]-mu)*rs*g4.x+b4.x;
        o.y=(cat[rid][c0+q*4+1]-mu)*rs*g4.y+b4.y;
        o.z=(cat[rid][c0+q*4+2]-mu)*rs*g4.z+b4.z;
        o.w=(cat[rid][c0+q*4+3]-mu)*rs*g4.w+b4.w;
        *(float4*)(h+(size_t)gn*128+c0+q*4)=o;
      }
    } }
  // coord update
  if(tid<32){
    int gn=g0+tid;
    if(gn<NN){
      float ci=cntinv[gn];
      x[gn*3+0]+=cacc[gn*3+0]*ci;
      x[gn*3+1]+=cacc[gn*3+1]*ci;
      x[gn*3+2]+=cacc[gn*3+2]*ci;
    }
  }
}

// ---- readout ----
__device__ __forceinline__ int lowerb(const int* a, int n, int v){
  int lo=0, hi=n;
  while(lo<hi){ int mid=(lo+hi)>>1; if(a[mid]<v) lo=mid+1; else hi=mid; }
  return lo;
}

__global__ void k_readout(const int* __restrict__ batch, const float* __restrict__ h,
                          const float* __restrict__ w1, const float* __restrict__ b1,
                          const float* __restrict__ w2, const float* __restrict__ b2,
                          const float* __restrict__ w3, const float* __restrict__ b3,
                          float* __restrict__ out){
  int g = blockIdx.x;
  int wl = threadIdx.x>>6, lane = threadIdx.x&63;
  __shared__ float part[4][128];
  __shared__ float gh[128];
  __shared__ float r1[128];
  __shared__ float r2[64];
  int start = lowerb(batch, NN, g);
  int end   = lowerb(batch, NN, g+1);
  float s0=0.f, s1=0.f;
  for(int n=start+wl; n<end; n+=4){
    s0 += h[(size_t)n*128+2*lane];
    s1 += h[(size_t)n*128+2*lane+1];
  }
  part[wl][2*lane]=s0; part[wl][2*lane+1]=s1;
  __syncthreads();
  float ci = 1.0f/fmaxf((float)(end-start),1.0f);
  if(wl==0){
    gh[2*lane]   = (part[0][2*lane]+part[1][2*lane]+part[2][2*lane]+part[3][2*lane])*ci;
    gh[2*lane+1] = (part[0][2*lane+1]+part[1][2*lane+1]+part[2][2*lane+1]+part[3][2*lane+1])*ci;
  }
  __syncthreads();
  if(wl==0){
    float a0=b1[2*lane], a1=b1[2*lane+1];
    for(int k=0;k<128;k++){
      float m=gh[k];
      float2 w=((const float2*)(w1+k*128))[lane];
      a0+=m*w.x; a1+=m*w.y;
    }
    r1[2*lane]=siluf(a0); r1[2*lane+1]=siluf(a1);
  }
  __syncthreads();
  if(wl==0){
    float b=b2[lane];
    for(int k=0;k<128;k++) b += r1[k]*w2[k*64+lane];
    r2[lane]=siluf(b);
  }
  __syncthreads();
  if(wl==0 && lane<2){
    float o=b3[lane];
    for(int k=0;k<64;k++) o += r2[k]*w3[k*2+lane];
    out[g*2+lane]=o;
  }
}

extern "C" void kernel_launch(void* const* d_in, const int* in_sizes, int n_in,
                              void* d_out, int out_size, void* d_ws, size_t ws_size,
                              hipStream_t stream){
  const float* nf     = (const float*)d_in[0];
  const float* coords = (const float*)d_in[1];
  const int*   ei     = (const int*)d_in[2];
  const float* ef     = (const float*)d_in[3];
  const int*   batch  = (const int*)d_in[4];

  const float* enc_w1 = (const float*)d_in[5];
  const float* enc_b1 = (const float*)d_in[6];
  const float* enc_w2 = (const float*)d_in[7];
  const float* enc_b2 = (const float*)d_in[8];
  const float* pe_w1  = (const float*)d_in[9];
  const float* pe_b1  = (const float*)d_in[10];
  const float* pe_w2  = (const float*)d_in[11];
  const float* pe_b2  = (const float*)d_in[12];
  const float* ph_w1  = (const float*)d_in[13];
  const float* ph_b1  = (const float*)d_in[14];
  const float* ph_w2  = (const float*)d_in[15];
  const float* ph_b2  = (const float*)d_in[16];
  const float* px_w1  = (const float*)d_in[17];
  const float* px_b1  = (const float*)d_in[18];
  const float* px_w2  = (const float*)d_in[19];
  const float* px_b2  = (const float*)d_in[20];
  const float* ln_g   = (const float*)d_in[21];
  const float* ln_b   = (const float*)d_in[22];
  const float* ro_w1  = (const float*)d_in[23];
  const float* ro_b1  = (const float*)d_in[24];
  const float* ro_w2  = (const float*)d_in[25];
  const float* ro_b2  = (const float*)d_in[26];
  const float* ro_w3  = (const float*)d_in[27];
  const float* ro_b3  = (const float*)d_in[28];

  char* wsb = (char*)d_ws;
  size_t off = 0;
  auto alloc_f = [&](size_t nfl)->float*{ float* p=(float*)(wsb+off); off+=nfl*4; return p; };
  auto alloc_i = [&](size_t nin)->int*  { int*   p=(int*)(wsb+off);   off+=nin*4; return p; };

  float* h      = alloc_f((size_t)NN*128);
  float* x      = alloc_f((size_t)NN*3);
  float* agg    = alloc_f((size_t)NN*64);
  float* cacc   = alloc_f((size_t)NN*3);
  float* cntinv = alloc_f(NN);
  float* pa     = alloc_f((size_t)NN*64);
  float* pb     = alloc_f((size_t)NN*64);
  float* wv     = alloc_f(NE);
  int* roff_dst = alloc_i(NN+1);
  int* roff_src = alloc_i(NN+1);
  int* dlist    = alloc_i(NE);
  int* slist    = alloc_i(NE);
  int* bsum     = alloc_i(256);
  int* bbase    = alloc_i(256);
  int* cnt_dst  = alloc_i(NN);   // cnt_dst..cur_src contiguous -> one memset
  int* cnt_src  = alloc_i(NN);
  int* cur_dst  = alloc_i(NN);
  int* cur_src  = alloc_i(NN);
  size_t base_bytes = off;
  float* msgbuf = (float*)(wsb + off);
  size_t cap_edges = (ws_size > base_bytes) ? (ws_size - base_bytes) / 256 : 0;

  int nchunks = 1;
  while (nchunks < 64 && (size_t)(NE/nchunks + 60000) > cap_edges) nchunks <<= 1;
  size_t chunk_cap = (size_t)NE/nchunks + 60000;
  if (chunk_cap > cap_edges) chunk_cap = cap_edges;
  int chunk_nodes = (NN + nchunks - 1) / nchunks;
  int gridA = (int)((chunk_cap + 255) / 256);

  hipMemsetAsync(cnt_dst, 0, (size_t)4*NN*sizeof(int), stream);
  k_degrees<<<(NE+255)/256,256,0,stream>>>(ei, cnt_dst, cnt_src);
  k_scan1<<<NB_SCAN,256,0,stream>>>(cnt_dst, roff_dst, bsum);
  k_scan2<<<1,256,0,stream>>>(bsum, bbase, roff_dst);
  k_scan3<<<NB_SCAN,256,0,stream>>>(roff_dst, bbase);
  k_scan1<<<NB_SCAN,256,0,stream>>>(cnt_src, roff_src, bsum);
  k_scan2<<<1,256,0,stream>>>(bsum, bbase, roff_src);
  k_scan3<<<NB_SCAN,256,0,stream>>>(roff_src, bbase);
  k_fill<<<(NE+255)/256,256,0,stream>>>(ei, roff_dst, roff_src, cur_dst, cur_src, dlist, slist);
  k_prep<<<(NN+255)/256,256,0,stream>>>(coords, cnt_dst, x, cntinv);
  k_encoder<<<(NN+31)/32,256,0,stream>>>(nf, enc_w1, enc_b1, enc_w2, enc_b2, h);

  for(int l=0;l<NL;l++){
    k_pre<<<(NN+31)/32,256,0,stream>>>(h, pe_w1+(size_t)l*273*64, pe_b1+l*64, pa, pb);
    for(int c=0;c<nchunks;c++){
      int n0 = c*chunk_nodes;
      int n1 = n0 + chunk_nodes; if (n1 > NN) n1 = NN;
      if (n0 >= NN) break;
      k_edgeA<<<gridA,256,0,stream>>>(ei, ef, x, pa, pb, roff_dst, dlist,
          pe_w1+(size_t)l*273*64,
          pe_w2+(size_t)l*64*64, pe_b2+l*64,
          px_w1+(size_t)l*64*64, px_b1+l*64,
          px_w2+l*64, px_b2+l,
          msgbuf, wv, n0, n1);
      k_aggB<<<(chunk_nodes+3)/4,256,0,stream>>>(msgbuf, roff_dst, cntinv, agg, n0, n1);
    }
    k_coordC<<<(NN+15)/16,256,0,stream>>>(ei, roff_src, slist, wv, x, cacc);
    k_node<<<(NN+31)/32,256,0,stream>>>(agg, cacc, cntinv,
        ph_w1+(size_t)l*192*128, ph_b1+l*128,
        ph_w2+(size_t)l*128*128, ph_b2+l*128,
        ln_g+l*128, ln_b+l*128, h, x);
  }

  k_readout<<<NG,256,0,stream>>>(batch, h,
      ro_w1, ro_b1, ro_w2, ro_b2, ro_w3, ro_b3, (float*)d_out);
}